// Round 13
// baseline (79.308 us; speedup 1.0000x reference)
//
#include <hip/hip_runtime.h>
#include <math.h>

#define LOG2E 1.4426950408889634f
#define LN2   0.6931471805599453f

typedef float v2f __attribute__((ext_vector_type(2)));

// Pass 1: grid = 256 blocks = (128 sample-groups) x (2 comp-halves).
// Block = 1024 threads = 16 waves; covers 512 samples (8/lane) x 512 comps
// (16 wave-chunks of 16 pairs). Records for this block's 512 comps are
// computed redundantly into LDS (12 KB); each wave reads each of its 16
// pair-records ONCE and applies it to 8 samples -> DS reads/eval = 3/16.
// Per-sample partial exp-sums (all terms <= 1, sum <= 512: linear-safe)
// go to part[half*N + sample] in d_ws.
__global__ __launch_bounds__(1024) void gm_pass1(
    const float* __restrict__ sample,     // (N,2)
    const float* __restrict__ mu,         // (M,2)
    const float* __restrict__ sigma_log,  // (M,2)
    const float* __restrict__ theta,      // (M,)
    const float* __restrict__ w,          // (M,1)
    float* __restrict__ part,             // (2*N,)
    int N, int M)
{
    __shared__ float4 recs4[256 * 3];     // 12 KB: 256 pair records
    __shared__ float  ws[16];
    __shared__ float  psum[16][512];      // 32 KB

    const int tid  = threadIdx.x;
    const int lane = tid & 63;
    const int wid  = tid >> 6;            // 0..15

    const int half = blockIdx.x & 1;      // comp half
    const int sg   = blockIdx.x >> 1;     // sample group
    const int s0g  = sg * 512;            // first sample of block
    const int m0   = half * (M >> 1);     // first comp of block

    // ---- load this lane's 8 samples (coalesced float2) ----
    const float2* sam = (const float2*)sample;
    float fxx[8], fxy[8], fyy[8], fsx[8], fsy[8];
    #pragma unroll
    for (int s = 0; s < 8; ++s) {
        const float2 sv = sam[s0g + lane + 64 * s];
        fxx[s] = sv.x * sv.x;
        fxy[s] = sv.x * sv.y;
        fyy[s] = sv.y * sv.y;
        fsx[s] = sv.x;
        fsy[s] = sv.y;
    }

    // ---- Phase 1: block logsumexp over all M w-values (1 per thread) ----
    const float wj = w[tid];
    float e = __expf(wj);                 // w ~ N(0,1): raw exp safe
    #pragma unroll
    for (int off = 32; off > 0; off >>= 1)
        e += __shfl_down(e, off, 64);
    if (lane == 0) ws[wid] = e;
    __syncthreads();
    float tot = 0.0f;
    #pragma unroll
    for (int k = 0; k < 16; ++k) tot += ws[k];
    const float lse = __logf(tot);

    // ---- Phase 2: records for this block's 512 comps (threads 0..511) ----
    if (tid < (M >> 1)) {
        const int j = m0 + tid;
        const float wjj = w[j];
        const float sl0 = sigma_log[2 * j + 0];
        const float sl1 = sigma_log[2 * j + 1];
        const float a = __expf(-2.0f * sl0);
        const float b = __expf(-2.0f * sl1);
        const float th = theta[j];
        const float c = __cosf(th);
        const float s = __sinf(th);

        const float g11 = a * c * c + b * s * s;
        const float g12 = (a - b) * c * s;
        const float g22 = a * s * s + b * c * c;

        const float mx = mu[2 * j + 0];
        const float my = mu[2 * j + 1];

        const float wlog = wjj - lse - (sl0 + sl1);

        const float A = g11;
        const float B = 2.0f * g12;
        const float C = g22;
        const float D = -(2.0f * g11 * mx + 2.0f * g12 * my);
        const float E = -(2.0f * g12 * mx + 2.0f * g22 * my);
        const float F = g11 * mx * mx + 2.0f * g12 * mx * my + g22 * my * my;
        const float K = (wlog - F) * LOG2E;

        float* recs = (float*)recs4;
        const int base = 12 * (tid >> 1) + (tid & 1);
        recs[base + 0]  = -A * LOG2E;
        recs[base + 2]  = -B * LOG2E;
        recs[base + 4]  = -C * LOG2E;
        recs[base + 6]  = -D * LOG2E;
        recs[base + 8]  = -E * LOG2E;
        recs[base + 10] = K;
    }
    __syncthreads();

    // ---- Phase 3: 16 pair-records x 8 samples per wave ----
    const int p0 = wid * 16;              // wave-uniform pair base

    v2f acc[8];
    #pragma unroll
    for (int s = 0; s < 8; ++s) acc[s] = (v2f)(0.0f);

    for (int p = 0; p < 16; ++p) {
        const float4* r4 = &recs4[3 * (p0 + p)];
        const float4 r0 = r4[0];          // A0 A1 B0 B1
        const float4 r1 = r4[1];          // C0 C1 D0 D1
        const float4 r2 = r4[2];          // E0 E1 K0 K1
        const v2f ra = {r0.x, r0.y};
        const v2f rb = {r0.z, r0.w};
        const v2f rc = {r1.x, r1.y};
        const v2f rd = {r1.z, r1.w};
        const v2f re = {r2.x, r2.y};
        const v2f rk = {r2.z, r2.w};

        #pragma unroll
        for (int s = 0; s < 8; ++s) {
            v2f ev = rk;
            ev = __builtin_elementwise_fma(ra, (v2f)(fxx[s]), ev);
            ev = __builtin_elementwise_fma(rb, (v2f)(fxy[s]), ev);
            ev = __builtin_elementwise_fma(rc, (v2f)(fyy[s]), ev);
            ev = __builtin_elementwise_fma(rd, (v2f)(fsx[s]), ev);
            ev = __builtin_elementwise_fma(re, (v2f)(fsy[s]), ev);
            v2f ex;
            ex.x = __builtin_amdgcn_exp2f(ev.x);
            ex.y = __builtin_amdgcn_exp2f(ev.y);
            acc[s] += ex;
        }
    }

    #pragma unroll
    for (int s = 0; s < 8; ++s)
        psum[wid][lane + 64 * s] = acc[s].x + acc[s].y;
    __syncthreads();

    // ---- Phase 4: combine 16 chunks -> partial sum per sample ----
    if (tid < 512) {
        float t = 0.0f;
        #pragma unroll
        for (int k = 0; k < 16; ++k) t += psum[k][tid];
        part[half * N + s0g + tid] = t;   // coalesced
    }
}

// Pass 2: t = part[i] + part[N+i]; nll -= ln(t); reduce; 1 atomic/block.
__global__ __launch_bounds__(1024) void gm_pass2(
    const float* __restrict__ part,       // (2*N,)
    float* __restrict__ out,
    int N)
{
    const int i = blockIdx.x * 1024 + threadIdx.x;
    const float t = part[i] + part[N + i];
    float v = -LN2 * __builtin_amdgcn_logf(t);

    #pragma unroll
    for (int off = 32; off > 0; off >>= 1)
        v += __shfl_down(v, off, 64);

    __shared__ float bs[16];
    const int lane = threadIdx.x & 63;
    const int wid  = threadIdx.x >> 6;
    if (lane == 0) bs[wid] = v;
    __syncthreads();
    if (threadIdx.x == 0) {
        float t2 = 0.0f;
        #pragma unroll
        for (int k = 0; k < 16; ++k) t2 += bs[k];
        atomicAdd(out, t2);
    }
}

extern "C" void kernel_launch(void* const* d_in, const int* in_sizes, int n_in,
                              void* d_out, int out_size, void* d_ws, size_t ws_size,
                              hipStream_t stream) {
    const float* sample    = (const float*)d_in[0];
    const float* mu        = (const float*)d_in[1];
    const float* sigma_log = (const float*)d_in[2];
    const float* theta     = (const float*)d_in[3];
    const float* w         = (const float*)d_in[4];
    float* out  = (float*)d_out;
    float* part = (float*)d_ws;

    const int M = in_sizes[3];      // 1024
    const int N = in_sizes[0] / 2;  // 65536

    // Zero the accumulator (harness poisons d_out before every launch).
    hipMemsetAsync(out, 0, sizeof(float), stream);

    // Pass 1: (N/512 sample groups) x (2 comp halves) blocks.
    const int grid1 = (N / 512) * 2;      // 256 blocks
    gm_pass1<<<grid1, 1024, 0, stream>>>(sample, mu, sigma_log, theta, w,
                                         part, N, M);

    // Pass 2: one thread per sample.
    const int grid2 = N / 1024;           // 64 blocks
    gm_pass2<<<grid2, 1024, 0, stream>>>(part, out, N);
}

// Round 14
// 77.073 us; speedup vs baseline: 1.0290x; 1.0290x over previous
//
#include <hip/hip_runtime.h>
#include <math.h>

#define LOG2E 1.4426950408889634f
#define LN2   0.6931471805599453f

typedef short bf8 __attribute__((ext_vector_type(8)));   // 8 bf16 = A/B frag
typedef float f4  __attribute__((ext_vector_type(4)));   // C/D frag

__device__ __forceinline__ unsigned short bf_hi(float x) {
    unsigned u = __float_as_uint(x);
    return (unsigned short)((u + 0x7FFFu + ((u >> 16) & 1u)) >> 16);
}

// add-reduce over the 16-lane DPP row; result lands in lane 15 of each row.
#define DPP_ADD(x, ctrl) \
    x += __int_as_float(__builtin_amdgcn_update_dpp(0, __float_as_int(x), ctrl, 0xF, 0xF, false))
__device__ __forceinline__ float row_sum16(float x) {
    DPP_ADD(x, 0x111);  // row_shr:1
    DPP_ADD(x, 0x112);  // row_shr:2
    DPP_ADD(x, 0x114);  // row_shr:4
    DPP_ADD(x, 0x118);  // row_shr:8
    return x;           // lane col==15 holds sum of its row's 16 lanes
}

// Single fused MFMA kernel. Grid = 256 blocks x 1024 threads (16 waves).
// Block: 256 samples x all M=1024 comps. e2[i,j] = X[i,.]*W[j,.] done as
// rank-6 GEMM via one mfma_f32_16x16x32_bf16 per 16x16 tile, with hi/lo
// bf16 split folded into K: A-slots [Xh(6) Xh(6) Xl(6) 0(14)],
// B-slots [Wh(6) Wl(6) Wh(6) 0(14)] -> XhWh + XhWl + XlWh in fp32.
// Wave wid owns 4 comp-tiles (64 comps), loops 16 sample-tiles; per tile:
// 4 mfma -> 16 exp2 -> DPP row-sum -> psum. Phase 4 combines, logs, atomics.
__global__ __launch_bounds__(1024) void gm_mfma(
    const float* __restrict__ sample,     // (N,2)
    const float* __restrict__ mu,         // (M,2)
    const float* __restrict__ sigma_log,  // (M,2)
    const float* __restrict__ theta,      // (M,)
    const float* __restrict__ w,          // (M,1)
    float* __restrict__ out,
    int M)
{
    // stride 40 shorts (=20 dwords) -> conflict-free b128 frag reads
    __shared__ __align__(16) unsigned short wrec[1024 * 40]; // 80 KB comps
    __shared__ __align__(16) unsigned short srec[256 * 40];  // 20 KB samples
    __shared__ float ws[16];
    __shared__ float psum[16 * 256];                         // 16 KB
    __shared__ float bsum[4];

    const int tid  = threadIdx.x;
    const int lane = tid & 63;
    const int wid  = tid >> 6;            // 0..15
    const int quad = lane >> 4;           // 0..3
    const int col  = lane & 15;           // 0..15

    // ---- Phase 1: block logsumexp over w ----
    const float wj = w[tid];
    float e = __expf(wj);                 // w ~ N(0,1): raw exp safe
    #pragma unroll
    for (int off = 32; off > 0; off >>= 1)
        e += __shfl_down(e, off, 64);
    if (lane == 0) ws[wid] = e;
    __syncthreads();
    float tot = 0.0f;
    #pragma unroll
    for (int k = 0; k < 16; ++k) tot += ws[k];
    const float lse = __logf(tot);

    // ---- Phase 2a: comp record for comp j = tid ----
    {
        const float sl0 = sigma_log[2 * tid + 0];
        const float sl1 = sigma_log[2 * tid + 1];
        const float a = __expf(-2.0f * sl0);
        const float b = __expf(-2.0f * sl1);
        const float th = theta[tid];
        const float c = __cosf(th);
        const float s = __sinf(th);

        const float g11 = a * c * c + b * s * s;
        const float g12 = (a - b) * c * s;
        const float g22 = a * s * s + b * c * c;

        const float mx = mu[2 * tid + 0];
        const float my = mu[2 * tid + 1];

        const float wlog = wj - lse - (sl0 + sl1);

        float cf[6];
        cf[0] = -g11 * LOG2E;                                  // * xx
        cf[1] = -2.0f * g12 * LOG2E;                           // * xy
        cf[2] = -g22 * LOG2E;                                  // * yy
        cf[3] = 2.0f * (g11 * mx + g12 * my) * LOG2E;          // * sx
        cf[4] = 2.0f * (g12 * mx + g22 * my) * LOG2E;          // * sy
        const float F = g11 * mx * mx + 2.0f * g12 * mx * my + g22 * my * my;
        cf[5] = (wlog - F) * LOG2E;                            // * 1

        unsigned short r[32];
        #pragma unroll
        for (int s2 = 0; s2 < 6; ++s2) {
            const unsigned short h = bf_hi(cf[s2]);
            const float hf = __uint_as_float((unsigned)h << 16);
            const unsigned short l = bf_hi(cf[s2] - hf);
            r[s2] = h; r[6 + s2] = l; r[12 + s2] = h;
        }
        #pragma unroll
        for (int s2 = 18; s2 < 32; ++s2) r[s2] = 0;
        unsigned* dst = (unsigned*)&wrec[tid * 40];
        #pragma unroll
        for (int k = 0; k < 16; ++k)
            dst[k] = ((unsigned)r[2 * k + 1] << 16) | r[2 * k];
    }

    // ---- Phase 2b: sample record (threads 0..255) ----
    if (tid < 256) {
        const float2 sv = ((const float2*)sample)[blockIdx.x * 256 + tid];
        float f[6];
        f[0] = sv.x * sv.x; f[1] = sv.x * sv.y; f[2] = sv.y * sv.y;
        f[3] = sv.x; f[4] = sv.y; f[5] = 1.0f;

        unsigned short r[32];
        #pragma unroll
        for (int s2 = 0; s2 < 6; ++s2) {
            const unsigned short h = bf_hi(f[s2]);
            const float hf = __uint_as_float((unsigned)h << 16);
            const unsigned short l = bf_hi(f[s2] - hf);
            r[s2] = h; r[6 + s2] = h; r[12 + s2] = l;
        }
        #pragma unroll
        for (int s2 = 18; s2 < 32; ++s2) r[s2] = 0;
        unsigned* dst = (unsigned*)&srec[tid * 40];
        #pragma unroll
        for (int k = 0; k < 16; ++k)
            dst[k] = ((unsigned)r[2 * k + 1] << 16) | r[2 * k];
    }
    __syncthreads();

    // ---- Phase 3: MFMA main loop ----
    bf8 bfrag[4];
    #pragma unroll
    for (int ct = 0; ct < 4; ++ct) {
        const int comp = wid * 64 + ct * 16 + col;
        bfrag[ct] = *(const bf8*)&wrec[comp * 40 + quad * 8];
    }

    const f4 zero = {0.0f, 0.0f, 0.0f, 0.0f};
    for (int st = 0; st < 16; ++st) {
        const bf8 afrag = *(const bf8*)&srec[(st * 16 + col) * 40 + quad * 8];
        float a0 = 0.0f, a1 = 0.0f, a2 = 0.0f, a3 = 0.0f;
        #pragma unroll
        for (int ct = 0; ct < 4; ++ct) {
            const f4 d = __builtin_amdgcn_mfma_f32_16x16x32_bf16(
                afrag, bfrag[ct], zero, 0, 0, 0);
            a0 += __builtin_amdgcn_exp2f(d[0]);
            a1 += __builtin_amdgcn_exp2f(d[1]);
            a2 += __builtin_amdgcn_exp2f(d[2]);
            a3 += __builtin_amdgcn_exp2f(d[3]);
        }
        // sum over the 16 comp-columns (lanes of the row)
        a0 = row_sum16(a0); a1 = row_sum16(a1);
        a2 = row_sum16(a2); a3 = row_sum16(a3);
        if (col == 15) {
            f4 o = {a0, a1, a2, a3};  // samples st*16 + quad*4 + 0..3
            *(f4*)&psum[wid * 256 + st * 16 + quad * 4] = o;
        }
    }
    __syncthreads();

    // ---- Phase 4: combine 16 waves per sample, log, reduce, atomic ----
    if (tid < 256) {
        float t = 0.0f;
        #pragma unroll
        for (int k = 0; k < 16; ++k) t += psum[k * 256 + tid];
        float v = -LN2 * __builtin_amdgcn_logf(t);
        #pragma unroll
        for (int off = 32; off > 0; off >>= 1)
            v += __shfl_down(v, off, 64);
        if ((tid & 63) == 0) bsum[tid >> 6] = v;
    }
    __syncthreads();
    if (tid == 0)
        atomicAdd(out, (bsum[0] + bsum[1]) + (bsum[2] + bsum[3]));
}

extern "C" void kernel_launch(void* const* d_in, const int* in_sizes, int n_in,
                              void* d_out, int out_size, void* d_ws, size_t ws_size,
                              hipStream_t stream) {
    const float* sample    = (const float*)d_in[0];
    const float* mu        = (const float*)d_in[1];
    const float* sigma_log = (const float*)d_in[2];
    const float* theta     = (const float*)d_in[3];
    const float* w         = (const float*)d_in[4];
    float* out = (float*)d_out;

    const int M = in_sizes[3];      // 1024
    const int N = in_sizes[0] / 2;  // 65536

    hipMemsetAsync(out, 0, sizeof(float), stream);

    const int grid = N / 256;       // 256 blocks, 1024 threads each
    gm_mfma<<<grid, 1024, 0, stream>>>(sample, mu, sigma_log, theta, w, out, M);
}